// Round 4
// baseline (289.194 us; speedup 1.0000x reference)
//
#include <hip/hip_runtime.h>
#include <hip/hip_bf16.h>
#include <math.h>

// Problem constants
constexpr int kB  = 2;
constexpr int kS  = 256;
constexpr int kH  = 8;
constexpr float kEPS = 1e-5f;

// Output offsets (floats) in d_out, in reference return order
constexpr int OFF_EST = 0;                         // (B,2,S,DV,H)   524288
constexpr int OFF_OUT = 524288;                    // (B,2,S,DE)     524288
constexpr int OFF_QIJ = 1048576;                   // (B,2,S,S,H)    2097152
constexpr int OFF_ZIJ = 3145728;                   // (B,2,S,S,DT)   134217728
constexpr int OFF_EPO = 137363456;                 // (2,512,1)      1024

// Workspace offsets (floats)
constexpr int WS_EFR = 0;          // (S,DT)
constexpr int WS_EFI = 131072;
constexpr int WS_EBR = 262144;     // reused later as A2P (bf16, 1 MB spans EBR+EBI)
constexpr int WS_EBI = 393216;
constexpr int WS_UQR = 524288;     // (B,H,S,DV)
constexpr int WS_UQI = 786432;
constexpr int WS_UKR = 1048576;    // (B,H,DV,S)  transposed
constexpr int WS_UKI = 1310720;
constexpr int WS_UVR = 1572864;    // (B,H,S,DV)
constexpr int WS_UVI = 1835008;
constexpr int WS_VR  = 2097152;    // (B,S,DV,H)
constexpr int WS_VI  = 2359296;
constexpr int WS_BF  = 3145728;    // bf16 region base (float offset)

// bf16-element offsets within bf16 region
constexpr int A2Q = 0;             // [512][1024]
constexpr int A2K = 524288;
constexpr int A2V = 1048576;
constexpr int B2R0 = 1572864;      // B2R(z) = B2R0 + z*1048576; B2I = +524288

typedef __attribute__((ext_vector_type(8))) short bf16x8;
typedef __attribute__((ext_vector_type(4))) float f32x4;
typedef __attribute__((ext_vector_type(8))) unsigned short u16x8;
typedef __attribute__((ext_vector_type(4))) unsigned short u16x4;

__device__ __forceinline__ float sigm(float x) { return 1.f / (1.f + expf(-x)); }
__device__ __forceinline__ unsigned short f2b(float f) {
    __hip_bfloat16 h = __float2bfloat16(f);
    return *reinterpret_cast<unsigned short*>(&h);
}

// ---------------------------------------------------------------------------
// Kernel 1 (fused prep): blocks 0..511 ef/eb+epoch, 512..1279 convA,
// 1280..1791 convW.
// ---------------------------------------------------------------------------
__global__ __launch_bounds__(256) void k_prep(
    const float* __restrict__ tall, const float* __restrict__ Lim,
    const float* __restrict__ Lre,
    const float* __restrict__ zq, const float* __restrict__ zk,
    const float* __restrict__ zv,
    const float* __restrict__ wq, const float* __restrict__ wk,
    const float* __restrict__ wv, const float* __restrict__ wp,
    float* __restrict__ efr, float* __restrict__ efi,
    float* __restrict__ ebr, float* __restrict__ ebi,
    float* __restrict__ epo, __hip_bfloat16* __restrict__ bfbase)
{
    __shared__ float s0[64][65];
    __shared__ float s1[64][65];
    const int bid = blockIdx.x;
    const int tid = threadIdx.x;

    if (bid < 512) {
        // ---- ef/eb precompute ----
        int idx = bid * 256 + tid;
        int s = idx >> 9;
        int c = idx & 511;
        int h = c >> 6;
        int d = c & 63;
        float li = (d < 32) ? Lim[h * 32 + d] : -Lim[h * 32 + d - 32];
        float lr = Lre[h];
        float t  = tall[s] / (tall[kS - 1] - tall[0]);
        float ph  = t * li;
        float mag = expf(t * lr);
        float cp  = cosf(ph);
        float sp  = sinf(ph);
        efr[idx] = mag * cp;
        efi[idx] = mag * sp;
        ebr[idx] = cp / mag;
        ebi[idx] = -sp / mag;
        if (s == 0) {
            epo[c]       = lr;
            epo[512 + c] = li;
        }
    } else if (bid < 1280) {
        // ---- convA: Zq/Zk/Zv -> bf16 [512][1024] ----
        int idx = (bid - 512) * 256 + tid;
        int tz  = idx >> 16;
        int rem = idx & 65535;
        int m   = rem >> 7;
        int k0  = (rem & 127) * 8;
        const float* src = (tz == 0) ? zq : (tz == 1) ? zk : zv;
        int b = m >> 8, s = m & 255;
        int c = (k0 >= 512) ? 1 : 0;
        int e = k0 - c * 512;
        const float* p = src + ((b * 2 + c) * 256 + s) * 512 + e;
        float4 v0 = *(const float4*)p;
        float4 v1 = *(const float4*)(p + 4);
        u16x8 o;
        o[0] = f2b(v0.x); o[1] = f2b(v0.y); o[2] = f2b(v0.z); o[3] = f2b(v0.w);
        o[4] = f2b(v1.x); o[5] = f2b(v1.y); o[6] = f2b(v1.z); o[7] = f2b(v1.w);
        __hip_bfloat16* dst = bfbase + ((tz == 0) ? A2Q : (tz == 1) ? A2K : A2V)
                              + m * 1024 + k0;
        *(u16x8*)dst = o;
    } else {
        // ---- convW: weights -> bf16 [512 n][1024 k] transposed ----
        int wid = bid - 1280;
        int z = wid >> 7;
        int r2 = wid & 127;
        int k0 = (r2 & 15) * 64;
        int n0 = (r2 >> 4) * 64;
        const float* W  = (z == 0) ? wq : (z == 1) ? wk : (z == 2) ? wv : wp;
        const float* W0 = W;
        const float* W1 = W + 262144;
        const int kp = k0 & 511;
        const bool hf = (k0 >= 512);
        const int r = tid >> 2;
        const int q = tid & 3;
#pragma unroll
        for (int c = 0; c < 4; ++c) {
            int col = q * 16 + c * 4;
            *(float4*)&s0[r][col] = *(const float4*)&W0[(kp + r) * 512 + n0 + col];
            *(float4*)&s1[r][col] = *(const float4*)&W1[(kp + r) * 512 + n0 + col];
        }
        __syncthreads();
        u16x8 r0, r1, i0, i1;
#pragma unroll
        for (int u = 0; u < 8; ++u) {
            int kl = q * 16 + u;
            float w0 = s0[kl][r], w1 = s1[kl][r];
            r0[u] = f2b(hf ? -w1 : w0);
            i0[u] = f2b(hf ?  w0 : w1);
        }
#pragma unroll
        for (int u = 0; u < 8; ++u) {
            int kl = q * 16 + 8 + u;
            float w0 = s0[kl][r], w1 = s1[kl][r];
            r1[u] = f2b(hf ? -w1 : w0);
            i1[u] = f2b(hf ?  w0 : w1);
        }
        __hip_bfloat16* pr = bfbase + B2R0 + z * 1048576
                             + (size_t)(n0 + r) * 1024 + k0 + q * 16;
        __hip_bfloat16* pi = pr + 524288;
        *(u16x8*)pr       = r0;
        *(u16x8*)(pr + 8) = r1;
        *(u16x8*)pi       = i0;
        *(u16x8*)(pi + 8) = i1;
    }
}

// ---------------------------------------------------------------------------
// Kernel 2: MFMA complex GEMM. Y(512x512 cplx) = A2[512x1024] @ (B2rT,B2iT)
// 64x64 block tile, 4 waves of 32x32, 16x16x32 bf16 MFMA, XOR-swizzled LDS.
// ---------------------------------------------------------------------------
template<bool IS_P>
__global__ __launch_bounds__(256) void k_cmfma(
    const __hip_bfloat16* __restrict__ bfbase,
    const __hip_bfloat16* __restrict__ a2p,
    const float* __restrict__ bq, const float* __restrict__ bk,
    const float* __restrict__ bv, const float* __restrict__ bp,
    const float* __restrict__ ebr, const float* __restrict__ ebi,
    float* __restrict__ uqr, float* __restrict__ uqi,
    float* __restrict__ ukr, float* __restrict__ uki,
    float* __restrict__ uvr, float* __restrict__ uvi,
    float* __restrict__ vr,  float* __restrict__ vi,
    float* __restrict__ outp)
{
    __shared__ __align__(16) char sm[24576];
    char* sA  = sm;
    char* sBr = sm + 8192;
    char* sBi = sm + 16384;

    const int mode = IS_P ? 3 : (int)blockIdx.z;
    const __hip_bfloat16* A2 = IS_P ? a2p
        : bfbase + ((mode == 0) ? A2Q : (mode == 1) ? A2K : A2V);
    const __hip_bfloat16* Br = bfbase + B2R0 + mode * 1048576;
    const __hip_bfloat16* Bi = Br + 524288;
    const float* bias = IS_P ? bp : ((mode == 0) ? bq : (mode == 1) ? bk : bv);

    const int tid = threadIdx.x;
    const int m0 = blockIdx.y * 64;
    const int n0 = blockIdx.x * 64;
    const int lane = tid & 63;
    const int wv2 = tid >> 6;
    const int wr = wv2 >> 1, wc = wv2 & 1;
    const int lx = lane & 15, lhi = lane >> 4;

    const int srow  = tid >> 2;
    const int sslot = (tid & 3) * 32;

    const char* gA  = (const char*)(A2 + (size_t)(m0 + srow) * 1024);
    const char* gBr = (const char*)(Br + (size_t)(n0 + srow) * 1024);
    const char* gBi = (const char*)(Bi + (size_t)(n0 + srow) * 1024);
    const int swz = (srow & 7) << 4;
    char* dA  = sA  + srow * 128;
    char* dBr = sBr + srow * 128;
    char* dBi = sBi + srow * 128;

    f32x4 accR[2][2] = {};
    f32x4 accI[2][2] = {};

    int rowA[2], rowB[2];
    rowA[0] = wr * 32 + lx;  rowA[1] = rowA[0] + 16;
    rowB[0] = wc * 32 + lx;  rowB[1] = rowB[0] + 16;

    for (int kt = 0; kt < 16; ++kt) {
        const int kb = kt * 128;
        {
            float4 a0 = *(const float4*)(gA  + kb + sslot);
            float4 a1 = *(const float4*)(gA  + kb + sslot + 16);
            float4 b0 = *(const float4*)(gBr + kb + sslot);
            float4 b1 = *(const float4*)(gBr + kb + sslot + 16);
            float4 c0 = *(const float4*)(gBi + kb + sslot);
            float4 c1 = *(const float4*)(gBi + kb + sslot + 16);
            *(float4*)(dA  + ( sslot       ^ swz)) = a0;
            *(float4*)(dA  + ((sslot + 16) ^ swz)) = a1;
            *(float4*)(dBr + ( sslot       ^ swz)) = b0;
            *(float4*)(dBr + ((sslot + 16) ^ swz)) = b1;
            *(float4*)(dBi + ( sslot       ^ swz)) = c0;
            *(float4*)(dBi + ((sslot + 16) ^ swz)) = c1;
        }
        __syncthreads();
#pragma unroll
        for (int kk = 0; kk < 2; ++kk) {
            const int kbyte = kk * 64 + lhi * 16;
            bf16x8 af[2], brf[2], bif[2];
#pragma unroll
            for (int x = 0; x < 2; ++x) {
                int ra = rowA[x];
                af[x]  = *(const bf16x8*)(sA  + ra * 128 + (kbyte ^ ((ra & 7) << 4)));
                int rb = rowB[x];
                brf[x] = *(const bf16x8*)(sBr + rb * 128 + (kbyte ^ ((rb & 7) << 4)));
                bif[x] = *(const bf16x8*)(sBi + rb * 128 + (kbyte ^ ((rb & 7) << 4)));
            }
#pragma unroll
            for (int a = 0; a < 2; ++a)
#pragma unroll
                for (int bb = 0; bb < 2; ++bb) {
                    accR[a][bb] = __builtin_amdgcn_mfma_f32_16x16x32_bf16(
                        af[a], brf[bb], accR[a][bb], 0, 0, 0);
                    accI[a][bb] = __builtin_amdgcn_mfma_f32_16x16x32_bf16(
                        af[a], bif[bb], accI[a][bb], 0, 0, 0);
                }
        }
        __syncthreads();
    }

#pragma unroll
    for (int a = 0; a < 2; ++a) {
#pragma unroll
        for (int bb = 0; bb < 2; ++bb) {
#pragma unroll
            for (int j = 0; j < 4; ++j) {
                int m = m0 + wr * 32 + a * 16 + lhi * 4 + j;
                int n = n0 + wc * 32 + bb * 16 + lx;
                float yr = accR[a][bb][j] + bias[n];
                float yi = accI[a][bb][j] + bias[512 + n];
                int b = m >> 8, s = m & 255;
                if (IS_P) {
                    int rowo = m * 512 + b * 131072;
                    outp[rowo + n] = yr;
                    outp[rowo + 131072 + n] = yi;
                } else {
                    int h = n >> 6, d = n & 63;
                    float er_ = ebr[s * 512 + n], ei_ = ebi[s * 512 + n];
                    float ur = er_ * yr - ei_ * yi;
                    float ui = er_ * yi + ei_ * yr;
                    if (mode == 0) {
                        int idx = ((b * 8 + h) * 256 + s) * 64 + d;
                        uqr[idx] = ur; uqi[idx] = ui;
                    } else if (mode == 1) {
                        int idx = ((b * 8 + h) * 64 + d) * 256 + s;
                        ukr[idx] = ur; uki[idx] = ui;
                    } else {
                        int idx = ((b * 8 + h) * 256 + s) * 64 + d;
                        uvr[idx] = ur; uvi[idx] = ui;
                        int vidx = (b * 256 + s) * 512 + d * 8 + h;
                        vr[vidx] = yr; vi[vidx] = yi;
                    }
                }
            }
        }
    }
}

// ---------------------------------------------------------------------------
// Kernel 3 (fused attention): scores -> softmax -> PV -> est_latent/a2p
// grid (16 i-tiles, 8 h, 2 b), 256 threads = 16 rows x 16 lanes.
// ---------------------------------------------------------------------------
__global__ __launch_bounds__(256) void k_attn(
    const float* __restrict__ uqr, const float* __restrict__ uqi,
    const float* __restrict__ ukr, const float* __restrict__ uki,
    const float* __restrict__ uvr, const float* __restrict__ uvi,
    const float* __restrict__ vr,  const float* __restrict__ vi,
    const float* __restrict__ tall,
    const float* __restrict__ Lre, const float* __restrict__ Lom,
    const float* __restrict__ Lga, const float* __restrict__ NF,
    const float* __restrict__ TAU, const float* __restrict__ ETA,
    const float* __restrict__ efr, const float* __restrict__ efi,
    float* __restrict__ qij, float* __restrict__ out_est,
    __hip_bfloat16* __restrict__ a2p)
{
    __shared__ float sQr[16][68];
    __shared__ float sQi[16][68];
    __shared__ float sS [16][260];
    __shared__ __align__(16) float sKr[64][68];
    __shared__ __align__(16) float sKi[64][68];

    const int it = blockIdx.x, h = blockIdx.y, b = blockIdx.z;
    const int i0 = it * 16;
    const int tid = threadIdx.x;
    const int ti = tid >> 4;
    const int tx = tid & 15;
    const int i  = i0 + ti;

    // stage Q tile (16 x 64 x 2)
    {
        const float* qsr = uqr + ((b * 8 + h) * 256 + i) * 64;
        const float* qsi = uqi + ((b * 8 + h) * 256 + i) * 64;
        *(float4*)&sQr[ti][tx * 4] = *(const float4*)&qsr[tx * 4];
        *(float4*)&sQi[ti][tx * 4] = *(const float4*)&qsi[tx * 4];
    }

    const float lre  = Lre[h];
    const float om   = Lom[h] * Lom[h];
    const float ga   = Lga[h] * Lga[h] + kEPS;
    const float nf2  = NF[h] * NF[h] + kEPS;
    const float tau2 = TAU[h] * TAU[h];
    const float den  = 2.f * lre;
    const float invT = 1.f / (tall[kS - 1] - tall[0]);
    const float t_i  = tall[i] * invT;
    const float m2i  = expf(2.f * t_i * lre);
    const bool  denok = fabsf(den) > 1e-6f;

    const int NT   = (it >> 2) + 1;    // 64-wide j tiles needed
    const int jlim = NT * 64;

    const int kd = tid >> 2;
    const int kq = (tid & 3) * 16;
    const float* kr_base = ukr + ((b * 8 + h) * 64 + kd) * 256;
    const float* ki_base = uki + ((b * 8 + h) * 64 + kd) * 256;

    for (int jt = 0; jt < NT; ++jt) {
        const int j0 = jt * 64;
        __syncthreads();
#pragma unroll
        for (int u = 0; u < 4; ++u) {
            *(float4*)&sKr[kd][kq + u * 4] = *(const float4*)&kr_base[j0 + kq + u * 4];
            *(float4*)&sKi[kd][kq + u * 4] = *(const float4*)&ki_base[j0 + kq + u * 4];
        }
        __syncthreads();

        float acc[4] = {0.f, 0.f, 0.f, 0.f};
#pragma unroll 8
        for (int d = 0; d < 64; ++d) {
            float qr = sQr[ti][d];
            float qi = sQi[ti][d];
            float4 kr = *(float4*)&sKr[d][tx * 4];
            float4 ki = *(float4*)&sKi[d][tx * 4];
#define DSTEP(c, KRC, KIC)                                    \
            { float dr = qr - KRC; float di = qi - KIC;       \
              acc[c] = fmaf(dr, dr, acc[c]);                  \
              acc[c] = fmaf(di, di, acc[c]); }
            DSTEP(0, kr.x, ki.x)
            DSTEP(1, kr.y, ki.y)
            DSTEP(2, kr.z, ki.z)
            DSTEP(3, kr.w, ki.w)
#undef DSTEP
        }

#pragma unroll
        for (int c = 0; c < 4; ++c) {
            int j = j0 + tx * 4 + c;
            float sc = -1e30f;
            if (j <= i) {
                float t_j = tall[j] * invT;
                float dtt = fmaxf(t_i - t_j, 0.f);
                float x = dtt * den;
                float g = denok ? (expm1f(x) / den) : dtt;
                float Vv = om * g + ga * expf(x);
                float base = nf2 * Vv + m2i * acc[c];
                sc = -tau2 * logf(base);
            }
            sS[ti][j] = sc;
        }
    }
    __syncthreads();

    // ---- row softmax (row = 16 contiguous lanes) ----
    float mx = -1e30f;
    for (int j = tx; j < jlim; j += 16) mx = fmaxf(mx, sS[ti][j]);
#pragma unroll
    for (int mask = 1; mask < 16; mask <<= 1) mx = fmaxf(mx, __shfl_xor(mx, mask));
    float l = 0.f;
    for (int j = tx; j < jlim; j += 16) l += expf(sS[ti][j] - mx);
#pragma unroll
    for (int mask = 1; mask < 16; mask <<= 1) l += __shfl_xor(l, mask);
    const float inv = 1.f / l;

    float* qr_out = qij + ((b * 512 + i) * 256) * 8 + h;
    float* qi_out = qij + ((b * 512 + 256 + i) * 256) * 8 + h;
    for (int j = tx; j < 256; j += 16) {
        float p = 0.f;
        if (j < jlim) {
            p = expf(sS[ti][j] - mx) * inv;
            sS[ti][j] = p;
        }
        qr_out[j * 8] = p;
        qi_out[j * 8] = 0.f;
    }
    __syncthreads();

    // ---- PV: er/ei[i][d] = sum_j p * Uv[j][d] (d = tx*4..+3) ----
    float accR[4] = {0.f, 0.f, 0.f, 0.f};
    float accI[4] = {0.f, 0.f, 0.f, 0.f};
    const float* vbr = uvr + ((b * 8 + h) * 256) * 64 + tx * 4;
    const float* vbi = uvi + ((b * 8 + h) * 256) * 64 + tx * 4;
    const int jmax = i0 + 16;
#pragma unroll 4
    for (int j = 0; j < jmax; ++j) {
        float a = sS[ti][j];
        float4 v = *(const float4*)&vbr[j * 64];
        float4 w = *(const float4*)&vbi[j * 64];
        accR[0] = fmaf(a, v.x, accR[0]);
        accR[1] = fmaf(a, v.y, accR[1]);
        accR[2] = fmaf(a, v.z, accR[2]);
        accR[3] = fmaf(a, v.w, accR[3]);
        accI[0] = fmaf(a, w.x, accI[0]);
        accI[1] = fmaf(a, w.y, accI[1]);
        accI[2] = fmaf(a, w.z, accI[2]);
        accI[3] = fmaf(a, w.w, accI[3]);
    }

    // ---- est_latent + a2p epilogue ----
    const int cbase = h * 64 + tx * 4;
    float4 fr = *(const float4*)&efr[i * 512 + cbase];
    float4 fi = *(const float4*)&efi[i * 512 + cbase];
    float4 mr4 = *(const float4*)&efr[cbase];
    float4 mi4 = *(const float4*)&efi[cbase];
    const float* frp = (const float*)&fr;
    const float* fip = (const float*)&fi;
    const float* mrp = (const float*)&mr4;
    const float* mip = (const float*)&mi4;
    u16x4 o_r, o_i;
#pragma unroll
    for (int c = 0; c < 4; ++c) {
        int d = tx * 4 + c;
        int p = d * 8 + h;
        float estr = frp[c] * accR[c] - fip[c] * accI[c];
        float esti = frp[c] * accI[c] + fip[c] * accR[c];
        float et = sigm(ETA[p]);
        float w1 = 1.f - et;
        float w2 = sigm(et);
        float vr_ = vr[(b * 256 + i) * 512 + p];
        float vi_ = vi[(b * 256 + i) * 512 + p];
        float elr = w1 * vr_ + w2 * estr;
        float eli = w1 * vi_ + w2 * esti;
        out_est[((b * 2 + 0) * 256 + i) * 512 + p] = elr;
        out_est[((b * 2 + 1) * 256 + i) * 512 + p] = eli;
        o_r[c] = f2b(mrp[c] * elr - mip[c] * eli);
        o_i[c] = f2b(mrp[c] * eli + mip[c] * elr);
    }
    __hip_bfloat16* ap = a2p + (b * 256 + i) * 1024 + cbase;
    *(u16x4*)ap         = o_r;
    *(u16x4*)(ap + 512) = o_i;
}

// ---------------------------------------------------------------------------
// Kernel 4: Z_ij streaming write (537 MB) — f32x4 nontemporal stores
// ---------------------------------------------------------------------------
__global__ __launch_bounds__(256) void k_zij(
    const float* __restrict__ efr, const float* __restrict__ efi,
    const float* __restrict__ uvr, const float* __restrict__ uvi,
    float* __restrict__ zout)
{
    const int b = blockIdx.z, i = blockIdx.y, j0 = blockIdx.x * 4;
    const int tid = threadIdx.x;
    const int jl = tid >> 6;          // 0..3
    const int q  = tid & 63;
    const int dt0 = q * 8;            // 0..504
    const int j = j0 + jl;
    const int h = q >> 3;
    const int d0 = (q & 7) * 8;

    f32x4 fr0 = *(const f32x4*)&efr[i * 512 + dt0];
    f32x4 fr1 = *(const f32x4*)&efr[i * 512 + dt0 + 4];
    f32x4 fi0 = *(const f32x4*)&efi[i * 512 + dt0];
    f32x4 fi1 = *(const f32x4*)&efi[i * 512 + dt0 + 4];

    const float* ur = uvr + ((b * 8 + h) * 256 + j) * 64 + d0;
    const float* ui = uvi + ((b * 8 + h) * 256 + j) * 64 + d0;
    f32x4 vr0 = *(const f32x4*)ur;
    f32x4 vr1 = *(const f32x4*)(ur + 4);
    f32x4 vi0 = *(const f32x4*)ui;
    f32x4 vi1 = *(const f32x4*)(ui + 4);

    f32x4 zr0 = fr0 * vr0 - fi0 * vi0;
    f32x4 zi0 = fr0 * vi0 + fi0 * vr0;
    f32x4 zr1 = fr1 * vr1 - fi1 * vi1;
    f32x4 zi1 = fr1 * vi1 + fi1 * vr1;

    const int base = (b * 2) * 33554432 + i * 131072 + j * 512 + dt0;
    __builtin_nontemporal_store(zr0, (f32x4*)&zout[base]);
    __builtin_nontemporal_store(zr1, (f32x4*)&zout[base + 4]);
    __builtin_nontemporal_store(zi0, (f32x4*)&zout[base + 33554432]);
    __builtin_nontemporal_store(zi1, (f32x4*)&zout[base + 33554432 + 4]);
}

// ---------------------------------------------------------------------------
extern "C" void kernel_launch(void* const* d_in, const int* in_sizes, int n_in,
                              void* d_out, int out_size, void* d_ws, size_t ws_size,
                              hipStream_t stream)
{
    const float* Zq   = (const float*)d_in[0];
    const float* Zk   = (const float*)d_in[1];
    const float* Zv   = (const float*)d_in[2];
    const float* tall = (const float*)d_in[3];
    const float* Wq   = (const float*)d_in[4];
    const float* bq   = (const float*)d_in[5];
    const float* Wk   = (const float*)d_in[6];
    const float* bk   = (const float*)d_in[7];
    const float* Wv   = (const float*)d_in[8];
    const float* bv   = (const float*)d_in[9];
    const float* Wp   = (const float*)d_in[10];
    const float* bp   = (const float*)d_in[11];
    const float* Lim  = (const float*)d_in[12];
    const float* Lre  = (const float*)d_in[13];
    const float* Lom  = (const float*)d_in[14];
    const float* Lga  = (const float*)d_in[15];
    const float* NF   = (const float*)d_in[16];
    const float* TAU  = (const float*)d_in[17];
    const float* ETA  = (const float*)d_in[18];

    float* out = (float*)d_out;
    float* ws  = (float*)d_ws;

    float* efr = ws + WS_EFR; float* efi = ws + WS_EFI;
    float* ebr = ws + WS_EBR; float* ebi = ws + WS_EBI;
    float* uqr = ws + WS_UQR; float* uqi = ws + WS_UQI;
    float* ukr = ws + WS_UKR; float* uki = ws + WS_UKI;
    float* uvr = ws + WS_UVR; float* uvi = ws + WS_UVI;
    float* vr  = ws + WS_VR;  float* vi  = ws + WS_VI;
    __hip_bfloat16* bfbase = (__hip_bfloat16*)(ws + WS_BF);
    __hip_bfloat16* a2p    = (__hip_bfloat16*)(ws + WS_EBR);  // reuse eb region

    k_prep<<<1792, 256, 0, stream>>>(tall, Lim, Lre, Zq, Zk, Zv,
                                     Wq, Wk, Wv, Wp,
                                     efr, efi, ebr, ebi,
                                     out + OFF_EPO, bfbase);

    k_cmfma<false><<<dim3(8, 8, 3), 256, 0, stream>>>(
        bfbase, nullptr, bq, bk, bv, bp, ebr, ebi,
        uqr, uqi, ukr, uki, uvr, uvi, vr, vi, nullptr);

    k_attn<<<dim3(16, 8, 2), 256, 0, stream>>>(
        uqr, uqi, ukr, uki, uvr, uvi, vr, vi,
        tall, Lre, Lom, Lga, NF, TAU, ETA, efr, efi,
        out + OFF_QIJ, out + OFF_EST, a2p);

    k_cmfma<true><<<dim3(8, 8, 1), 256, 0, stream>>>(
        bfbase, a2p, bq, bk, bv, bp, ebr, ebi,
        nullptr, nullptr, nullptr, nullptr, nullptr, nullptr, nullptr, nullptr,
        out + OFF_OUT);

    k_zij<<<dim3(64, 256, 2), 256, 0, stream>>>(efr, efi, uvr, uvi,
                                                out + OFF_ZIJ);
}